// Round 1
// baseline (1111.589 us; speedup 1.0000x reference)
//
#include <hip/hip_runtime.h>
#include <math.h>

#define NL 28
#define NB 3
#define NH 16
#define NS 1024
#define ND 128
#define VOCAB 151936
#define HIST 64

#define CHUNKS 64
#define CHUNK_LEN (VOCAB / CHUNKS)   // 2374

// d_out flat fp32 layout (element offsets)
#define OFF_TOK  176160768   // tok_col (3)
#define OFF_SAVE 176160771   // save_id_out (3*65)
#define OFF_RP   176160966   // rp (3*151936)
#define OFF_PROB 176616774   // top_beam_prob (3)
#define OFF_MAX  176616777   // max_logits_idx (1)

// workspace word layout:
// partial (b,c): base=(b*CHUNKS+c)*8 -> [0]=m [1]=l [2..4]=v [5..7]=idx  (max word 1535)
#define WS_BEAM 1536
#define WS_TOK  1540

typedef float f32x4 __attribute__((ext_vector_type(4)));

__device__ __forceinline__ void ins3(float x, int ix, float v[3], int iv[3]) {
    if (x > v[0] || (x == v[0] && ix < iv[0])) {
        v[2] = v[1]; iv[2] = iv[1];
        v[1] = v[0]; iv[1] = iv[0];
        v[0] = x;    iv[0] = ix;
    } else if (x > v[1] || (x == v[1] && ix < iv[1])) {
        v[2] = v[1]; iv[2] = iv[1];
        v[1] = x;    iv[1] = ix;
    } else if (x > v[2] || (x == v[2] && ix < iv[2])) {
        v[2] = x;    iv[2] = ix;
    }
}

// K1: per (batch-row, chunk) partial reduction: online softmax state + top-3
__global__ __launch_bounds__(256) void k1_partial(
    const float* __restrict__ logits, const float* __restrict__ rpen,
    float* __restrict__ wsf, int* __restrict__ wsi) {
    const int b = blockIdx.x / CHUNKS;
    const int c = blockIdx.x % CHUNKS;
    const int base = c * CHUNK_LEN;
    const float* lrow = logits + b * VOCAB;
    const float* prow = rpen + b * VOCAB;

    float m = -INFINITY, l = 0.f;
    float v[3] = {-INFINITY, -INFINITY, -INFINITY};
    int iv[3] = {-1, -1, -1};

    for (int j = threadIdx.x; j < CHUNK_LEN; j += 256) {
        int idx = base + j;
        float x = lrow[idx] * prow[idx];
        if (x > m) { l = l * expf(m - x) + 1.f; m = x; }
        else       { l += expf(x - m); }
        ins3(x, idx, v, iv);
    }

    // wave-level (64-lane) reduce
    for (int off = 32; off > 0; off >>= 1) {
        float om = __shfl_down(m, off, 64);
        float ol = __shfl_down(l, off, 64);
        float ov[3]; int oi[3];
#pragma unroll
        for (int k = 0; k < 3; ++k) {
            ov[k] = __shfl_down(v[k], off, 64);
            oi[k] = __shfl_down(iv[k], off, 64);
        }
        float M = fmaxf(m, om);
        l = l * expf(m - M) + ol * expf(om - M);
        m = M;
#pragma unroll
        for (int k = 0; k < 3; ++k) ins3(ov[k], oi[k], v, iv);
    }

    __shared__ float sm[4], sl[4], sv[4][3];
    __shared__ int si[4][3];
    const int lane = threadIdx.x & 63;
    const int wid = threadIdx.x >> 6;
    if (lane == 0) {
        sm[wid] = m; sl[wid] = l;
#pragma unroll
        for (int k = 0; k < 3; ++k) { sv[wid][k] = v[k]; si[wid][k] = iv[k]; }
    }
    __syncthreads();
    if (threadIdx.x == 0) {
        for (int w = 1; w < 4; ++w) {
            float M = fmaxf(m, sm[w]);
            l = l * expf(m - M) + sl[w] * expf(sm[w] - M);
            m = M;
#pragma unroll
            for (int k = 0; k < 3; ++k) ins3(sv[w][k], si[w][k], v, iv);
        }
        const int pbase = (b * CHUNKS + c) * 8;
        wsf[pbase + 0] = m;
        wsf[pbase + 1] = l;
#pragma unroll
        for (int k = 0; k < 3; ++k) {
            wsf[pbase + 2 + k] = v[k];
            wsi[pbase + 5 + k] = iv[k];
        }
    }
}

// K2: merge partials -> per-row top3 lp; beam select; write small outputs
__global__ __launch_bounds__(256) void k2_select(
    const float* __restrict__ prev, const int* __restrict__ save_id,
    const float* __restrict__ wsf, int* __restrict__ wsi,
    float* __restrict__ out) {
    __shared__ float stopv[9];
    __shared__ int stopi[9];
    __shared__ int sbeam[3], stok[3];
    __shared__ float sprob[3];
    const int t = threadIdx.x;

    if (t < NB) {
        float m = -INFINITY, l = 0.f;
        float v[3] = {-INFINITY, -INFINITY, -INFINITY};
        int iv[3] = {-1, -1, -1};
        for (int c = 0; c < CHUNKS; ++c) {
            const int pbase = (t * CHUNKS + c) * 8;
            float pm = wsf[pbase + 0], pl = wsf[pbase + 1];
            float M = fmaxf(m, pm);
            l = l * expf(m - M) + pl * expf(pm - M);
            m = M;
#pragma unroll
            for (int k = 0; k < 3; ++k) ins3(wsf[pbase + 2 + k], wsi[pbase + 5 + k], v, iv);
        }
        const float lse = m + logf(l);
#pragma unroll
        for (int k = 0; k < 3; ++k) {
            stopv[t * 3 + k] = v[k] - lse;
            stopi[t * 3 + k] = iv[k];
        }
    }
    __syncthreads();
    if (t == 0) {
        float cur[9];
        for (int j = 0; j < 9; ++j) cur[j] = stopv[j] + prev[j / 3];
        bool used[9] = {false, false, false, false, false, false, false, false, false};
        for (int i = 0; i < 3; ++i) {
            int best = 0; float bv = -INFINITY;
            for (int j = 0; j < 9; ++j) {
                if (!used[j] && cur[j] > bv) { bv = cur[j]; best = j; }
            }
            used[best] = true;
            sbeam[i] = best / 3;
            stok[i]  = stopi[best];
            sprob[i] = bv;
        }
        for (int i = 0; i < 3; ++i) {
            wsi[WS_BEAM + i] = sbeam[i];
            wsi[WS_TOK + i]  = stok[i];
        }
    }
    __syncthreads();
    if (t < 3) {
        out[OFF_TOK + t]  = (float)stok[t];
        out[OFF_PROB + t] = sprob[t];
    }
    if (t == 0) out[OFF_MAX] = (float)stok[0];
    if (t < 3 * (HIST + 1)) {
        const int i = t / (HIST + 1);
        const int h = t - i * (HIST + 1);
        out[OFF_SAVE + t] = (h < HIST) ? (float)save_id[sbeam[i] * HIST + h]
                                       : (float)stok[i];
    }
}

// K3 (fused with old K4): kv gather-copy, 8x float4 per thread (128 B),
// nontemporal streaming; tail blocks do the rp gather + token penalty.
#define PER4      ((NH * NS * ND) / 4)        // 524288 = 1<<19 float4 per (l,i)
#define KV4       (NL * NB * PER4)            // 44,040,192 float4 total
#define KVBLOCKS  (KV4 / 2048)                // 21504 (2048 float4 = 8 per thread)
#define RPBLOCKS  ((NB * VOCAB + 255) / 256)  // 1781

__global__ __launch_bounds__(256) void k3_fused(
    const f32x4* __restrict__ kv, const float* __restrict__ rpen,
    const float* __restrict__ pen, const int* __restrict__ wsi,
    f32x4* __restrict__ out4, float* __restrict__ out) {
    if (blockIdx.x < KVBLOCKS) {
        // 256 blocks per (l,i) run of 2^19 float4s
        const unsigned li = blockIdx.x >> 8;          // 0..83 = l*3+i
        const unsigned l  = li / 3u;
        const unsigned i  = li - l * 3u;
        const int sb = wsi[WS_BEAM + i];              // wave-uniform, L2 hit
        const unsigned dst = blockIdx.x * 2048u + threadIdx.x;
        const unsigned src = (l * 3u + (unsigned)sb) * PER4
                           + (blockIdx.x & 255u) * 2048u + threadIdx.x;
        f32x4 r[8];
#pragma unroll
        for (int k = 0; k < 8; ++k)
            r[k] = __builtin_nontemporal_load(&kv[src + k * 256u]);
#pragma unroll
        for (int k = 0; k < 8; ++k)
            __builtin_nontemporal_store(r[k], &out4[dst + k * 256u]);
    } else {
        const int idx = (blockIdx.x - KVBLOCKS) * 256 + threadIdx.x;
        if (idx < NB * VOCAB) {
            const int i = idx / VOCAB;
            const int v = idx - i * VOCAB;
            float x = rpen[wsi[WS_BEAM + i] * VOCAB + v];
            if (v == wsi[WS_TOK + i]) x *= pen[0];
            out[OFF_RP + idx] = x;
        }
    }
}

extern "C" void kernel_launch(void* const* d_in, const int* in_sizes, int n_in,
                              void* d_out, int out_size, void* d_ws, size_t ws_size,
                              hipStream_t stream) {
    const float* kv      = (const float*)d_in[0];
    const float* logits  = (const float*)d_in[1];
    const int*   save_id = (const int*)d_in[2];
    const float* rpen    = (const float*)d_in[3];
    const float* prev    = (const float*)d_in[4];
    const float* pen     = (const float*)d_in[5];
    float* out = (float*)d_out;
    float* wsf = (float*)d_ws;
    int*   wsi = (int*)d_ws;

    k1_partial<<<NB * CHUNKS, 256, 0, stream>>>(logits, rpen, wsf, wsi);
    k2_select<<<1, 256, 0, stream>>>(prev, save_id, wsf, wsi, out);
    k3_fused<<<KVBLOCKS + RPBLOCKS, 256, 0, stream>>>(
        (const f32x4*)kv, rpen, pen, wsi, (f32x4*)out, out);
}

// Round 2
// 1110.111 us; speedup vs baseline: 1.0013x; 1.0013x over previous
//
#include <hip/hip_runtime.h>
#include <math.h>

#define NL 28
#define NB 3
#define NH 16
#define NS 1024
#define ND 128
#define VOCAB 151936
#define HIST 64

#define CHUNKS 64
#define CHUNK_LEN (VOCAB / CHUNKS)   // 2374

// d_out flat fp32 layout (element offsets)
#define OFF_TOK  176160768   // tok_col (3)
#define OFF_SAVE 176160771   // save_id_out (3*65)
#define OFF_RP   176160966   // rp (3*151936)
#define OFF_PROB 176616774   // top_beam_prob (3)
#define OFF_MAX  176616777   // max_logits_idx (1)

// workspace word layout:
// partial (b,c): base=(b*CHUNKS+c)*8 -> [0]=m [1]=l [2..4]=v [5..7]=idx  (max word 1535)
#define WS_BEAM 1536
#define WS_TOK  1540

typedef float f32x4 __attribute__((ext_vector_type(4)));

__device__ __forceinline__ void ins3(float x, int ix, float v[3], int iv[3]) {
    if (x > v[0] || (x == v[0] && ix < iv[0])) {
        v[2] = v[1]; iv[2] = iv[1];
        v[1] = v[0]; iv[1] = iv[0];
        v[0] = x;    iv[0] = ix;
    } else if (x > v[1] || (x == v[1] && ix < iv[1])) {
        v[2] = v[1]; iv[2] = iv[1];
        v[1] = x;    iv[1] = ix;
    } else if (x > v[2] || (x == v[2] && ix < iv[2])) {
        v[2] = x;    iv[2] = ix;
    }
}

// K1: per (batch-row, chunk) partial reduction: online softmax state + top-3
__global__ __launch_bounds__(256) void k1_partial(
    const float* __restrict__ logits, const float* __restrict__ rpen,
    float* __restrict__ wsf, int* __restrict__ wsi) {
    const int b = blockIdx.x / CHUNKS;
    const int c = blockIdx.x % CHUNKS;
    const int base = c * CHUNK_LEN;
    const float* lrow = logits + b * VOCAB;
    const float* prow = rpen + b * VOCAB;

    float m = -INFINITY, l = 0.f;
    float v[3] = {-INFINITY, -INFINITY, -INFINITY};
    int iv[3] = {-1, -1, -1};

    for (int j = threadIdx.x; j < CHUNK_LEN; j += 256) {
        int idx = base + j;
        float x = lrow[idx] * prow[idx];
        if (x > m) { l = l * expf(m - x) + 1.f; m = x; }
        else       { l += expf(x - m); }
        ins3(x, idx, v, iv);
    }

    // wave-level (64-lane) reduce
    for (int off = 32; off > 0; off >>= 1) {
        float om = __shfl_down(m, off, 64);
        float ol = __shfl_down(l, off, 64);
        float ov[3]; int oi[3];
#pragma unroll
        for (int k = 0; k < 3; ++k) {
            ov[k] = __shfl_down(v[k], off, 64);
            oi[k] = __shfl_down(iv[k], off, 64);
        }
        float M = fmaxf(m, om);
        l = l * expf(m - M) + ol * expf(om - M);
        m = M;
#pragma unroll
        for (int k = 0; k < 3; ++k) ins3(ov[k], oi[k], v, iv);
    }

    __shared__ float sm[4], sl[4], sv[4][3];
    __shared__ int si[4][3];
    const int lane = threadIdx.x & 63;
    const int wid = threadIdx.x >> 6;
    if (lane == 0) {
        sm[wid] = m; sl[wid] = l;
#pragma unroll
        for (int k = 0; k < 3; ++k) { sv[wid][k] = v[k]; si[wid][k] = iv[k]; }
    }
    __syncthreads();
    if (threadIdx.x == 0) {
        for (int w = 1; w < 4; ++w) {
            float M = fmaxf(m, sm[w]);
            l = l * expf(m - M) + sl[w] * expf(sm[w] - M);
            m = M;
#pragma unroll
            for (int k = 0; k < 3; ++k) ins3(sv[w][k], si[w][k], v, iv);
        }
        const int pbase = (b * CHUNKS + c) * 8;
        wsf[pbase + 0] = m;
        wsf[pbase + 1] = l;
#pragma unroll
        for (int k = 0; k < 3; ++k) {
            wsf[pbase + 2 + k] = v[k];
            wsi[pbase + 5 + k] = iv[k];
        }
    }
}

// K2: merge partials -> per-row top3 lp; beam select; write small outputs
__global__ __launch_bounds__(256) void k2_select(
    const float* __restrict__ prev, const int* __restrict__ save_id,
    const float* __restrict__ wsf, int* __restrict__ wsi,
    float* __restrict__ out) {
    __shared__ float stopv[9];
    __shared__ int stopi[9];
    __shared__ int sbeam[3], stok[3];
    __shared__ float sprob[3];
    const int t = threadIdx.x;

    if (t < NB) {
        float m = -INFINITY, l = 0.f;
        float v[3] = {-INFINITY, -INFINITY, -INFINITY};
        int iv[3] = {-1, -1, -1};
        for (int c = 0; c < CHUNKS; ++c) {
            const int pbase = (t * CHUNKS + c) * 8;
            float pm = wsf[pbase + 0], pl = wsf[pbase + 1];
            float M = fmaxf(m, pm);
            l = l * expf(m - M) + pl * expf(pm - M);
            m = M;
#pragma unroll
            for (int k = 0; k < 3; ++k) ins3(wsf[pbase + 2 + k], wsi[pbase + 5 + k], v, iv);
        }
        const float lse = m + logf(l);
#pragma unroll
        for (int k = 0; k < 3; ++k) {
            stopv[t * 3 + k] = v[k] - lse;
            stopi[t * 3 + k] = iv[k];
        }
    }
    __syncthreads();
    if (t == 0) {
        float cur[9];
        for (int j = 0; j < 9; ++j) cur[j] = stopv[j] + prev[j / 3];
        bool used[9] = {false, false, false, false, false, false, false, false, false};
        for (int i = 0; i < 3; ++i) {
            int best = 0; float bv = -INFINITY;
            for (int j = 0; j < 9; ++j) {
                if (!used[j] && cur[j] > bv) { bv = cur[j]; best = j; }
            }
            used[best] = true;
            sbeam[i] = best / 3;
            stok[i]  = stopi[best];
            sprob[i] = bv;
        }
        for (int i = 0; i < 3; ++i) {
            wsi[WS_BEAM + i] = sbeam[i];
            wsi[WS_TOK + i]  = stok[i];
        }
    }
    __syncthreads();
    if (t < 3) {
        out[OFF_TOK + t]  = (float)stok[t];
        out[OFF_PROB + t] = sprob[t];
    }
    if (t == 0) out[OFF_MAX] = (float)stok[0];
    if (t < 3 * (HIST + 1)) {
        const int i = t / (HIST + 1);
        const int h = t - i * (HIST + 1);
        out[OFF_SAVE + t] = (h < HIST) ? (float)save_id[sbeam[i] * HIST + h]
                                       : (float)stok[i];
    }
}

// K3: persistent grid-stride kv gather-copy (the proven 6.3 TB/s recipe:
// ~2048 blocks, plain float4 loads/stores, unroll-4 for MLP), with the
// rp gather + token penalty folded in as a single-pass tail.
//
// PER4 = 2^19 f4 per (l,beam) slab; grid stride = 2048*256 = 2^19 exactly,
// so iteration k copies exactly slab k (k = l*3+i, 0..83) and the gather
// indirection is one wave-uniform LDS lookup per slab.
#define PER4      ((NH * NS * ND) / 4)        // 524288 = 1<<19 float4 per (l,i)
#define NSLAB     (NL * NB)                   // 84
#define KVBLOCKS  2048

__global__ __launch_bounds__(256) void k3_fused(
    const f32x4* __restrict__ kv, const float* __restrict__ rpen,
    const float* __restrict__ pen, const int* __restrict__ wsi,
    f32x4* __restrict__ out4, float* __restrict__ out) {
    __shared__ int smap[NSLAB];   // smap[l*3+i] = l*3 + beam[i]
    __shared__ int sbeam[3], stok[3];
    const int t = threadIdx.x;
    if (t < 3) {
        sbeam[t] = wsi[WS_BEAM + t];
        stok[t]  = wsi[WS_TOK + t];
    }
    __syncthreads();
    if (t < NSLAB) {
        const int l = t / 3;
        const int i = t - l * 3;
        smap[t] = l * 3 + sbeam[i];
    }
    __syncthreads();

    const unsigned p = blockIdx.x * 256u + (unsigned)t;   // 0 .. 2^19-1

#pragma unroll 1
    for (int k = 0; k < NSLAB; k += 4) {
        const size_t s0 = (size_t)smap[k + 0] * PER4 + p;
        const size_t s1 = (size_t)smap[k + 1] * PER4 + p;
        const size_t s2 = (size_t)smap[k + 2] * PER4 + p;
        const size_t s3 = (size_t)smap[k + 3] * PER4 + p;
        f32x4 r0 = kv[s0];
        f32x4 r1 = kv[s1];
        f32x4 r2 = kv[s2];
        f32x4 r3 = kv[s3];
        out4[(size_t)(k + 0) * PER4 + p] = r0;
        out4[(size_t)(k + 1) * PER4 + p] = r1;
        out4[(size_t)(k + 2) * PER4 + p] = r2;
        out4[(size_t)(k + 3) * PER4 + p] = r3;
    }

    // rp tail: NB*VOCAB = 455808 < 2^19, so one element per thread max.
    if (p < NB * VOCAB) {
        const int i = p / VOCAB;
        const int v = (int)p - i * VOCAB;
        float x = rpen[sbeam[i] * VOCAB + v];
        if (v == stok[i]) x *= pen[0];
        out[OFF_RP + p] = x;
    }
}

extern "C" void kernel_launch(void* const* d_in, const int* in_sizes, int n_in,
                              void* d_out, int out_size, void* d_ws, size_t ws_size,
                              hipStream_t stream) {
    const float* kv      = (const float*)d_in[0];
    const float* logits  = (const float*)d_in[1];
    const int*   save_id = (const int*)d_in[2];
    const float* rpen    = (const float*)d_in[3];
    const float* prev    = (const float*)d_in[4];
    const float* pen     = (const float*)d_in[5];
    float* out = (float*)d_out;
    float* wsf = (float*)d_ws;
    int*   wsi = (int*)d_ws;

    k1_partial<<<NB * CHUNKS, 256, 0, stream>>>(logits, rpen, wsf, wsi);
    k2_select<<<1, 256, 0, stream>>>(prev, save_id, wsf, wsi, out);
    k3_fused<<<KVBLOCKS, 256, 0, stream>>>(
        (const f32x4*)kv, rpen, pen, wsi, (f32x4*)out, out);
}

// Round 5
// 1090.780 us; speedup vs baseline: 1.0191x; 1.0177x over previous
//
#include <hip/hip_runtime.h>
#include <math.h>

#define NL 28
#define NB 3
#define NH 16
#define NS 1024
#define ND 128
#define VOCAB 151936
#define HIST 64

#define CHUNKS 16
#define CHUNK_LEN (VOCAB / CHUNKS)   // 9496

// d_out flat fp32 layout (element offsets)
#define OFF_TOK  176160768   // tok_col (3)
#define OFF_SAVE 176160771   // save_id_out (3*65)
#define OFF_RP   176160966   // rp (3*151936)
#define OFF_PROB 176616774   // top_beam_prob (3)
#define OFF_MAX  176616777   // max_logits_idx (1)

// workspace word layout:
// partial (b,c): base=(b*CHUNKS+c)*8 -> [0]=m [1]=l [2..4]=v [5..7]=idx
// wsi[384..386] = beam_index, wsi[388..390] = tokens
#define WS_BEAM 384
#define WS_TOK  388

typedef float f32x4 __attribute__((ext_vector_type(4)));

__device__ __forceinline__ void ins3(float x, int ix, float v[3], int iv[3]) {
    if (x > v[0] || (x == v[0] && ix < iv[0])) {
        v[2] = v[1]; iv[2] = iv[1];
        v[1] = v[0]; iv[1] = iv[0];
        v[0] = x;    iv[0] = ix;
    } else if (x > v[1] || (x == v[1] && ix < iv[1])) {
        v[2] = v[1]; iv[2] = iv[1];
        v[1] = x;    iv[1] = ix;
    } else if (x > v[2] || (x == v[2] && ix < iv[2])) {
        v[2] = x;    iv[2] = ix;
    }
}

// K1: per (batch-row, chunk) partial reduction: online softmax state + top-3
__global__ __launch_bounds__(256) void k1_partial(
    const float* __restrict__ logits, const float* __restrict__ rpen,
    float* __restrict__ wsf, int* __restrict__ wsi) {
    const int b = blockIdx.x / CHUNKS;
    const int c = blockIdx.x % CHUNKS;
    const int base = c * CHUNK_LEN;
    const float* lrow = logits + b * VOCAB;
    const float* prow = rpen + b * VOCAB;

    float m = -INFINITY, l = 0.f;
    float v[3] = {-INFINITY, -INFINITY, -INFINITY};
    int iv[3] = {-1, -1, -1};

    for (int j = threadIdx.x; j < CHUNK_LEN; j += 256) {
        int idx = base + j;
        float x = lrow[idx] * prow[idx];
        if (x > m) { l = l * expf(m - x) + 1.f; m = x; }
        else       { l += expf(x - m); }
        ins3(x, idx, v, iv);
    }

    // wave-level (64-lane) reduce
    for (int off = 32; off > 0; off >>= 1) {
        float om = __shfl_down(m, off, 64);
        float ol = __shfl_down(l, off, 64);
        float ov[3]; int oi[3];
#pragma unroll
        for (int k = 0; k < 3; ++k) {
            ov[k] = __shfl_down(v[k], off, 64);
            oi[k] = __shfl_down(iv[k], off, 64);
        }
        float M = fmaxf(m, om);
        l = l * expf(m - M) + ol * expf(om - M);
        m = M;
#pragma unroll
        for (int k = 0; k < 3; ++k) ins3(ov[k], oi[k], v, iv);
    }

    __shared__ float sm[4], sl[4], sv[4][3];
    __shared__ int si[4][3];
    const int lane = threadIdx.x & 63;
    const int wid = threadIdx.x >> 6;
    if (lane == 0) {
        sm[wid] = m; sl[wid] = l;
#pragma unroll
        for (int k = 0; k < 3; ++k) { sv[wid][k] = v[k]; si[wid][k] = iv[k]; }
    }
    __syncthreads();
    if (threadIdx.x == 0) {
        for (int w = 1; w < 4; ++w) {
            float M = fmaxf(m, sm[w]);
            l = l * expf(m - M) + sl[w] * expf(sm[w] - M);
            m = M;
#pragma unroll
            for (int k = 0; k < 3; ++k) ins3(sv[w][k], si[w][k], v, iv);
        }
        const int pbase = (b * CHUNKS + c) * 8;
        wsf[pbase + 0] = m;
        wsf[pbase + 1] = l;
#pragma unroll
        for (int k = 0; k < 3; ++k) {
            wsf[pbase + 2 + k] = v[k];
            wsi[pbase + 5 + k] = iv[k];
        }
    }
}

// K2: merge partials -> per-row top3 lp; beam select; write small outputs
__global__ __launch_bounds__(256) void k2_select(
    const float* __restrict__ prev, const int* __restrict__ save_id,
    const float* __restrict__ wsf, int* __restrict__ wsi,
    float* __restrict__ out) {
    __shared__ float stopv[9];
    __shared__ int stopi[9];
    __shared__ int sbeam[3], stok[3];
    __shared__ float sprob[3];
    const int t = threadIdx.x;

    if (t < NB) {
        float m = -INFINITY, l = 0.f;
        float v[3] = {-INFINITY, -INFINITY, -INFINITY};
        int iv[3] = {-1, -1, -1};
        for (int c = 0; c < CHUNKS; ++c) {
            const int pbase = (t * CHUNKS + c) * 8;
            float pm = wsf[pbase + 0], pl = wsf[pbase + 1];
            float M = fmaxf(m, pm);
            l = l * expf(m - M) + pl * expf(pm - M);
            m = M;
#pragma unroll
            for (int k = 0; k < 3; ++k) ins3(wsf[pbase + 2 + k], wsi[pbase + 5 + k], v, iv);
        }
        const float lse = m + logf(l);
#pragma unroll
        for (int k = 0; k < 3; ++k) {
            stopv[t * 3 + k] = v[k] - lse;
            stopi[t * 3 + k] = iv[k];
        }
    }
    __syncthreads();
    if (t == 0) {
        float cur[9];
        for (int j = 0; j < 9; ++j) cur[j] = stopv[j] + prev[j / 3];
        bool used[9] = {false, false, false, false, false, false, false, false, false};
        for (int i = 0; i < 3; ++i) {
            int best = 0; float bv = -INFINITY;
            for (int j = 0; j < 9; ++j) {
                if (!used[j] && cur[j] > bv) { bv = cur[j]; best = j; }
            }
            used[best] = true;
            sbeam[i] = best / 3;
            stok[i]  = stopi[best];
            sprob[i] = bv;
        }
        for (int i = 0; i < 3; ++i) {
            wsi[WS_BEAM + i] = sbeam[i];
            wsi[WS_TOK + i]  = stok[i];
        }
    }
    __syncthreads();
    if (t < 3) {
        out[OFF_TOK + t]  = (float)stok[t];
        out[OFF_PROB + t] = sprob[t];
    }
    if (t == 0) out[OFF_MAX] = (float)stok[0];
    if (t < 3 * (HIST + 1)) {
        const int i = t / (HIST + 1);
        const int h = t - i * (HIST + 1);
        out[OFF_SAVE + t] = (h < HIST) ? (float)save_id[sbeam[i] * HIST + h]
                                       : (float)stok[i];
    }
}

// K3: persistent grid-stride kv gather-copy (m13 recipe: 2048 blocks,
// plain float4 loads/stores, 4 independent loads in flight per thread).
// PER4 = 2^19 f4 per (l,beam) slab; grid stride = 2048*256 = 2^19 exactly,
// so iteration k copies exactly slab k (k = l*3+i, 0..83) and the gather
// indirection is one wave-uniform LDS lookup per slab.
#define PER4      ((NH * NS * ND) / 4)        // 524288 = 1<<19 float4 per (l,i)
#define NSLAB     (NL * NB)                   // 84
#define KVBLOCKS  2048

__global__ __launch_bounds__(256) void k3_kv(
    const f32x4* __restrict__ kv, const int* __restrict__ wsi,
    f32x4* __restrict__ out4) {
    __shared__ int smap[NSLAB];   // smap[l*3+i] = l*3 + beam[i]
    __shared__ int sbeam[3];
    const int t = threadIdx.x;
    if (t < 3) sbeam[t] = wsi[WS_BEAM + t];
    __syncthreads();
    if (t < NSLAB) {
        const int l = t / 3;
        const int i = t - l * 3;
        smap[t] = l * 3 + sbeam[i];
    }
    __syncthreads();

    const unsigned p = blockIdx.x * 256u + (unsigned)t;   // 0 .. 2^19-1

#pragma unroll 1
    for (int k = 0; k < NSLAB; k += 4) {
        const size_t s0 = (size_t)smap[k + 0] * PER4 + p;
        const size_t s1 = (size_t)smap[k + 1] * PER4 + p;
        const size_t s2 = (size_t)smap[k + 2] * PER4 + p;
        const size_t s3 = (size_t)smap[k + 3] * PER4 + p;
        f32x4 r0 = kv[s0];
        f32x4 r1 = kv[s1];
        f32x4 r2 = kv[s2];
        f32x4 r3 = kv[s3];
        out4[(size_t)(k + 0) * PER4 + p] = r0;
        out4[(size_t)(k + 1) * PER4 + p] = r1;
        out4[(size_t)(k + 2) * PER4 + p] = r2;
        out4[(size_t)(k + 3) * PER4 + p] = r3;
    }
}

// K4: rp gather + token penalty
__global__ __launch_bounds__(256) void k4_rp(
    const float* __restrict__ rpen, const float* __restrict__ pen,
    const int* __restrict__ wsi, float* __restrict__ out) {
    int idx = blockIdx.x * 256 + threadIdx.x;
    if (idx >= NB * VOCAB) return;
    int i = idx / VOCAB;
    int v = idx - i * VOCAB;
    float x = rpen[wsi[WS_BEAM + i] * VOCAB + v];
    if (v == wsi[WS_TOK + i]) x *= pen[0];
    out[OFF_RP + idx] = x;
}

extern "C" void kernel_launch(void* const* d_in, const int* in_sizes, int n_in,
                              void* d_out, int out_size, void* d_ws, size_t ws_size,
                              hipStream_t stream) {
    const float* kv      = (const float*)d_in[0];
    const float* logits  = (const float*)d_in[1];
    const int*   save_id = (const int*)d_in[2];
    const float* rpen    = (const float*)d_in[3];
    const float* prev    = (const float*)d_in[4];
    const float* pen     = (const float*)d_in[5];
    float* out = (float*)d_out;
    float* wsf = (float*)d_ws;
    int*   wsi = (int*)d_ws;

    k1_partial<<<NB * CHUNKS, 256, 0, stream>>>(logits, rpen, wsf, wsi);
    k2_select<<<1, 256, 0, stream>>>(prev, save_id, wsf, wsi, out);
    k3_kv<<<KVBLOCKS, 256, 0, stream>>>((const f32x4*)kv, wsi, (f32x4*)out);
    k4_rp<<<(NB * VOCAB + 255) / 256, 256, 0, stream>>>(rpen, pen, wsi, out);
}